// Round 1
// baseline (83.405 us; speedup 1.0000x reference)
//
#include <hip/hip_runtime.h>

// CrossCompress: B=16384, D=128, fp32.
// item_out[b,:]   = v * (e.w_vv) + e * (v.w_ev) + bias_v
// entity_out[b,:] = v * (e.w_ve) + e * (v.w_ee) + bias_e
//
// Layout: 32 lanes per row (float4 each => 128 floats = one row),
// 2 rows per wave64, 8 rows per 256-thread block, grid = B/8 = 2048 blocks.
// Shuffle-reduce (xor 16..1) stays within each 32-lane half of the wave.

#define BROWS 16384
#define DDIM  128

__global__ __launch_bounds__(256) void cross_compress_kernel(
    const float* __restrict__ v_in,    // item_embedding   [B,D]
    const float* __restrict__ e_in,    // entity_embedding [B,D]
    const float* __restrict__ w_vv,    // [D]
    const float* __restrict__ w_ve,
    const float* __restrict__ w_ev,
    const float* __restrict__ w_ee,
    const float* __restrict__ bias_v,
    const float* __restrict__ bias_e,
    float* __restrict__ out)           // [2,B,D] flat: item_out then entity_out
{
    const int lane = threadIdx.x & 63;
    const int wave = threadIdx.x >> 6;     // 0..3
    const int half = lane >> 5;            // which row within this wave
    const int sub  = lane & 31;            // 0..31 -> float4 slot

    const int row = blockIdx.x * 8 + wave * 2 + half;   // grid sized exactly
    const int col = sub * 4;

    const float4 v4  = *reinterpret_cast<const float4*>(v_in  + row * DDIM + col);
    const float4 e4  = *reinterpret_cast<const float4*>(e_in  + row * DDIM + col);
    const float4 wvv = *reinterpret_cast<const float4*>(w_vv + col);
    const float4 wve = *reinterpret_cast<const float4*>(w_ve + col);
    const float4 wev = *reinterpret_cast<const float4*>(w_ev + col);
    const float4 wee = *reinterpret_cast<const float4*>(w_ee + col);
    const float4 bv  = *reinterpret_cast<const float4*>(bias_v + col);
    const float4 be  = *reinterpret_cast<const float4*>(bias_e + col);

    // Per-lane partial dot products
    float s_vv = e4.x*wvv.x + e4.y*wvv.y + e4.z*wvv.z + e4.w*wvv.w;  // e . w_vv
    float s_ev = v4.x*wev.x + v4.y*wev.y + v4.z*wev.z + v4.w*wev.w;  // v . w_ev
    float s_ve = e4.x*wve.x + e4.y*wve.y + e4.z*wve.z + e4.w*wve.w;  // e . w_ve
    float s_ee = v4.x*wee.x + v4.y*wee.y + v4.z*wee.z + v4.w*wee.w;  // v . w_ee

    // Butterfly reduction within each 32-lane half (offsets <= 16 never cross
    // the half-wave boundary).
    #pragma unroll
    for (int off = 16; off >= 1; off >>= 1) {
        s_vv += __shfl_xor(s_vv, off, 64);
        s_ev += __shfl_xor(s_ev, off, 64);
        s_ve += __shfl_xor(s_ve, off, 64);
        s_ee += __shfl_xor(s_ee, off, 64);
    }

    float4 io, eo;
    io.x = v4.x * s_vv + e4.x * s_ev + bv.x;
    io.y = v4.y * s_vv + e4.y * s_ev + bv.y;
    io.z = v4.z * s_vv + e4.z * s_ev + bv.z;
    io.w = v4.w * s_vv + e4.w * s_ev + bv.w;

    eo.x = v4.x * s_ve + e4.x * s_ee + be.x;
    eo.y = v4.y * s_ve + e4.y * s_ee + be.y;
    eo.z = v4.z * s_ve + e4.z * s_ee + be.z;
    eo.w = v4.w * s_ve + e4.w * s_ee + be.w;

    *reinterpret_cast<float4*>(out + (size_t)row * DDIM + col) = io;
    *reinterpret_cast<float4*>(out + (size_t)BROWS * DDIM + (size_t)row * DDIM + col) = eo;
}

extern "C" void kernel_launch(void* const* d_in, const int* in_sizes, int n_in,
                              void* d_out, int out_size, void* d_ws, size_t ws_size,
                              hipStream_t stream) {
    const float* v_in   = (const float*)d_in[0];
    const float* e_in   = (const float*)d_in[1];
    const float* w_vv   = (const float*)d_in[2];
    const float* w_ve   = (const float*)d_in[3];
    const float* w_ev   = (const float*)d_in[4];
    const float* w_ee   = (const float*)d_in[5];
    const float* bias_v = (const float*)d_in[6];
    const float* bias_e = (const float*)d_in[7];
    float* out = (float*)d_out;

    // 8 rows per 256-thread block
    const int grid = BROWS / 8;   // 2048
    cross_compress_kernel<<<grid, 256, 0, stream>>>(
        v_in, e_in, w_vv, w_ve, w_ev, w_ee, bias_v, bias_e, out);
}